// Round 6
// baseline (2258.131 us; speedup 1.0000x reference)
//
#include <hip/hip_runtime.h>
#include <stdint.h>

typedef unsigned short u16;
typedef unsigned short u16x4 __attribute__((ext_vector_type(4)));
typedef short bf16x8 __attribute__((ext_vector_type(8)));
typedef float f32x4 __attribute__((ext_vector_type(4)));

#define CDIM 256
#define MSZ 65536
#define NBLK 20

// ---------------- ws layout (bytes) ----------------
constexpr size_t O_XB   = 0;                       // 64MB x bf16 NHWC
constexpr size_t O_AT   = 67108864;                // fp32 A^T (dead after scale)
constexpr size_t O_PQH  = 67108864;                // alias AT
constexpr size_t O_PQL  = O_PQH + 524288;
constexpr size_t O_SVAL = 68419584;
constexpr size_t O_W0   = 68419840;                // h,l,th,tl each 655360 B
constexpr size_t O_W1   = 71041280;
constexpr size_t O_PH   = 71041280;                // alias W1 (dead after bjorck)
constexpr size_t O_PL   = O_PH + 524288;
constexpr size_t O_QTH  = O_PL + 524288;
constexpr size_t O_QTL  = O_QTH + 524288;
constexpr size_t O_TH   = 73662720;
constexpr size_t O_TL   = O_TH + 655360;
constexpr size_t O_C1H  = 73662720;                // alias T (dead after bjorck)
constexpr size_t O_C1L  = O_C1H + 131072;
constexpr size_t O_C2H  = O_C1L + 131072;
constexpr size_t O_C2L  = O_C2H + 131072;
constexpr size_t O_C2TH = O_C2L + 131072;
constexpr size_t O_C2TL = O_C2TH + 131072;
constexpr size_t O_RTH  = 74973440;
constexpr size_t O_RTL  = O_RTH + 1179648;
constexpr size_t O_WBQ  = O_RTL + 1179648;
constexpr size_t O_BAR  = O_WBQ + 1179648;         // counters; flags at +1024

__device__ __forceinline__ u16 f2bf(float f) {
  union { float f; uint32_t u; } a; a.f = f;
  uint32_t u = a.u;
  uint32_t r = u + 0x7FFFu + ((u >> 16) & 1u);
  return (u16)(r >> 16);
}
__device__ __forceinline__ float bf2f(u16 u) {
  union { uint32_t u; float f; } a; a.u = ((uint32_t)u) << 16; return a.f;
}
__device__ __forceinline__ void split_st(u16* hi, u16* lo, float v) {
  u16 h = f2bf(v);
  *hi = h;
  *lo = f2bf(v - bf2f(h));
}

// grid barrier: 20 arrivals on counter; last sets release flag; pollers use
// pure agent-scope loads. ~2s bailout so a lost block can't wedge the GPU.
__device__ __forceinline__ void grid_bar(uint32_t* cnt, uint32_t* flag, int idx) {
  __syncthreads();
  if (threadIdx.x == 0) {
    __threadfence();
    uint32_t prev = atomicAdd(&cnt[idx], 1u);
    if (prev + 1u == (uint32_t)NBLK) {
      __threadfence();
      __hip_atomic_store(&flag[idx], 1u, __ATOMIC_RELAXED, __HIP_MEMORY_SCOPE_AGENT);
    } else {
      uint64_t t0 = 0; uint32_t spins = 0;
      while (__hip_atomic_load(&flag[idx], __ATOMIC_RELAXED, __HIP_MEMORY_SCOPE_AGENT) == 0u) {
        __builtin_amdgcn_s_sleep(2);
        if (((++spins) & 255u) == 0u) {
          uint64_t now = __builtin_amdgcn_s_memrealtime();
          if (!t0) t0 = now;
          else if (now - t0 > 200000000ull) break;
        }
      }
    }
    __threadfence();
  }
  __syncthreads();
}

// ---------------- x: NCHW f32 -> NHWC bf16 ----------------
__global__ void convert_k(const float* __restrict__ x, u16* __restrict__ xb) {
  __shared__ float t[32][33];
  int b = blockIdx.x;
  int ctile = b & 7, wtile = (b >> 3) & 1, h = (b >> 4) & 63, n = b >> 10;
  int c0 = ctile * 32, w0 = wtile * 32;
  int tid = threadIdx.x;
  for (int p = 0; p < 4; p++) {
    int e = tid + p * 256; int cc = e >> 5, ww = e & 31;
    t[cc][ww] = x[(((size_t)n * 256 + c0 + cc) * 64 + h) * 64 + w0 + ww];
  }
  __syncthreads();
  for (int p = 0; p < 4; p++) {
    int e = tid + p * 256; int ww = e >> 5, cc = e & 31;
    xb[(((size_t)n * 64 + h) * 64 + w0 + ww) * 256 + c0 + cc] = f2bf(t[cc][ww]);
  }
}

// ---------------- hi/lo-split MFMA 128x128-tile GEMM: C += A·B^T ----------------
// A/B stored [row][k] k-contiguous bf16 (hi+lo). 4 waves (2x2), each owns a
// 64x64 quadrant: acc[4][4] of 16x16 frags. K staged in 32-elem chunks,
// 2-deep reg prefetch + double-buffered LDS. LDS row = 64B, swizzle
// slot ^= (row>>1)&3 -> 2-way (free) bank access on ds_read_b128.
template<int NC>
__device__ __forceinline__ void gemm128(
    const u16* __restrict__ Ah, const u16* __restrict__ Al, int i0,
    const u16* __restrict__ Bh, const u16* __restrict__ Bl, int j0,
    f32x4 (*acc)[4], char* smem, int tid)
{
  int lane = tid & 63, wave = tid >> 6;
  int wm = wave >> 1, wn = wave & 1;
  int fr = lane & 15, q = lane >> 4;
  uint4 rgA[8], rgB[8];

  auto gload = [&](int c, uint4* rg) {
    int kcb = c * 64;                      // byte offset of k-chunk in a row
    #pragma unroll
    for (int p = 0; p < 8; ++p) {
      int e = tid + p * 256;
      int bufi = e >> 9;                   // 0:Ah 1:Al 2:Bh 3:Bl
      int r = (e >> 2) & 127;
      int s = e & 3;
      const u16* srcm = (bufi == 0) ? Ah : (bufi == 1) ? Al : (bufi == 2) ? Bh : Bl;
      int r0 = (bufi < 2) ? i0 : j0;
      rg[p] = *(const uint4*)((const char*)srcm + (size_t)(r0 + r) * 512 + kcb + s * 16);
    }
  };
  auto lstore = [&](int db, const uint4* rg) {
    #pragma unroll
    for (int p = 0; p < 8; ++p) {
      int e = tid + p * 256;
      int bufi = e >> 9;
      int r = (e >> 2) & 127;
      int s = e & 3;
      *(uint4*)(smem + db * 32768 + bufi * 8192 + r * 64 + ((s ^ ((r >> 1) & 3)) << 4)) = rg[p];
    }
  };

  gload(0, rgA);
  lstore(0, rgA);
  gload(1, rgB);
  #pragma unroll
  for (int c = 0; c < NC; ++c) {
    __syncthreads();                       // buf[c&1] stores visible
    if (c + 2 < NC) gload(c + 2, (c & 1) ? rgB : rgA);
    int db = c & 1;
    bf16x8 ah[4], al[4], bh[4], bl[4];
    #pragma unroll
    for (int f = 0; f < 4; ++f) {
      int ra = wm * 64 + f * 16 + fr;
      int oa = db * 32768 + ra * 64 + ((q ^ ((ra >> 1) & 3)) << 4);
      ah[f] = *(const bf16x8*)(smem + oa);
      al[f] = *(const bf16x8*)(smem + 8192 + oa);
      int rb = wn * 64 + f * 16 + fr;
      int ob = db * 32768 + rb * 64 + ((q ^ ((rb >> 1) & 3)) << 4);
      bh[f] = *(const bf16x8*)(smem + 16384 + ob);
      bl[f] = *(const bf16x8*)(smem + 24576 + ob);
    }
    #pragma unroll
    for (int fm = 0; fm < 4; ++fm)
      #pragma unroll
      for (int fn = 0; fn < 4; ++fn) {
        acc[fm][fn] = __builtin_amdgcn_mfma_f32_16x16x32_bf16(ah[fm], bh[fn], acc[fm][fn], 0, 0, 0);
        acc[fm][fn] = __builtin_amdgcn_mfma_f32_16x16x32_bf16(ah[fm], bl[fn], acc[fm][fn], 0, 0, 0);
        acc[fm][fn] = __builtin_amdgcn_mfma_f32_16x16x32_bf16(al[fm], bh[fn], acc[fm][fn], 0, 0, 0);
      }
    if (c + 1 < NC) lstore((c + 1) & 1, (c & 1) ? rgA : rgB);
  }
}

// ---------------- the whole weight chain: one 20-block kernel ----------------
__global__ __launch_bounds__(256, 1) void weight_k(const float* __restrict__ param,
                                                   const float* __restrict__ u0,
                                                   char* __restrict__ ws) {
  __shared__ char smem[65536];
  int bid = blockIdx.x, tid = threadIdx.x;
  int lane = tid & 63, wave = tid >> 6;
  int wm = wave >> 1, wn = wave & 1;
  uint32_t* cnt = (uint32_t*)(ws + O_BAR);
  uint32_t* flg = (uint32_t*)(ws + O_BAR + 1024);
  int bseq = 0;

  float* At = (float*)(ws + O_AT);
  float* sval = (float*)(ws + O_SVAL);
  u16* W0h  = (u16*)(ws + O_W0);
  u16* W0l  = W0h + 327680;
  u16* W0th = W0l + 327680;
  u16* W0tl = W0th + 327680;
  u16* W1h  = (u16*)(ws + O_W1);
  u16* W1l  = W1h + 327680;
  u16* W1th = W1l + 327680;
  u16* W1tl = W1th + 327680;
  u16* Th = (u16*)(ws + O_TH);
  u16* Tl = (u16*)(ws + O_TL);
  u16* PQh = (u16*)(ws + O_PQH);
  u16* PQl = (u16*)(ws + O_PQL);
  u16* C1h = (u16*)(ws + O_C1H);  u16* C1l = (u16*)(ws + O_C1L);
  u16* C2h = (u16*)(ws + O_C2H);  u16* C2l = (u16*)(ws + O_C2L);
  u16* C2th = (u16*)(ws + O_C2TH); u16* C2tl = (u16*)(ws + O_C2TL);
  u16* Ph = (u16*)(ws + O_PH);  u16* Pl = (u16*)(ws + O_PL);
  u16* QTh = (u16*)(ws + O_QTH); u16* QTl = (u16*)(ws + O_QTL);
  u16* RTh = (u16*)(ws + O_RTH); u16* RTl = (u16*)(ws + O_RTL);
  u16* WBQ = (u16*)(ws + O_WBQ);

  // C-frag element indices (16x16x32 D-layout)
  int orow = wm * 64 + ((lane >> 4) << 2);   // + fm*16 + v
  int ocol = wn * 64 + (lane & 15);          // + fn*16

  // ---- stage 0: At = A^T (fp32, for power iteration) ----
  {
    float (*t)[33] = (float(*)[33])smem;
    for (int job = bid; job < 320; job += NBLK) {
      int m = job >> 6, tile = job & 63;
      int i0 = (tile >> 3) * 32, j0 = (tile & 7) * 32;
      const float* Am = param + (size_t)m * MSZ;
      float* Atm = At + (size_t)m * MSZ;
      __syncthreads();
      for (int p = 0; p < 4; ++p) {
        int e = tid + p * 256; int ii = e >> 5, jj = e & 31;
        t[ii][jj] = Am[(i0 + ii) * CDIM + j0 + jj];
      }
      __syncthreads();
      for (int p = 0; p < 4; ++p) {
        int e = tid + p * 256; int jj = e >> 5, ii = e & 31;
        Atm[(j0 + jj) * CDIM + i0 + ii] = t[ii][jj];
      }
    }
  }
  grid_bar(cnt, flg, bseq++);

  // ---- stage 1: power iteration (fp32, block-local, 5 blocks) ----
  if (bid < 5) {
    float* u = (float*)smem;
    float* v = u + 256;
    float* red = v + 256;
    const float* Am = param + (size_t)bid * MSZ;
    const float* Atm = At + (size_t)bid * MSZ;
    int t = tid;
    u[t] = u0[bid * 256 + t];
    __syncthreads();
    float nu = 1.0f;
    for (int it = 0; it < 10; ++it) {
      float a1 = 0.f;
      #pragma unroll 4
      for (int i = 0; i < 256; i++) a1 += Am[i * 256 + t] * u[i];
      float ss = a1 * a1;
      for (int off = 32; off; off >>= 1) ss += __shfl_down(ss, off);
      __syncthreads();
      if ((t & 63) == 0) red[t >> 6] = ss;
      __syncthreads();
      float nv = sqrtf(red[0] + red[1] + red[2] + red[3]);
      v[t] = a1 / nv;
      __syncthreads();
      float a2 = 0.f;
      #pragma unroll 4
      for (int j = 0; j < 256; j++) a2 += Atm[j * 256 + t] * v[j];
      float s2 = a2 * a2;
      for (int off = 32; off; off >>= 1) s2 += __shfl_down(s2, off);
      __syncthreads();
      if ((t & 63) == 0) red[t >> 6] = s2;
      __syncthreads();
      nu = sqrtf(red[0] + red[1] + red[2] + red[3]);
      u[t] = a2 / nu;
      __syncthreads();
    }
    if (t == 0) sval[bid] = nu;   // sigma = u^T A v = ||Av|| = last norm
  }
  grid_bar(cnt, flg, bseq++);

  // ---- stage 2: scale + hi/lo split (W and W^T) ----
  {
    for (size_t idx = (size_t)bid * 256 + tid; idx < 327680; idx += NBLK * 256) {
      int m = (int)(idx >> 16);
      float inv = 1.0f / sval[m];
      float v = param[idx] * inv;
      split_st(&W0h[idx], &W0l[idx], v);
      float vt = At[idx] * inv;
      split_st(&W0th[idx], &W0tl[idx], vt);
    }
  }
  grid_bar(cnt, flg, bseq++);

  // ---- stage 3: Bjorck, 20 iterations (5 matrices x 4 tiles = 20 blocks) ----
  u16 *cWh = W0h, *cWl = W0l, *cWth = W0th, *cWtl = W0tl;
  u16 *nWh = W1h, *nWl = W1l, *nWth = W1th, *nWtl = W1tl;
  int m5 = bid >> 2, tile5 = bid & 3;
  int bi0 = (tile5 >> 1) * 128, bj0 = (tile5 & 1) * 128;
  size_t mo = (size_t)m5 * MSZ;
  for (int it = 0; it < 20; ++it) {
    {  // T = W^T W  (A = B = Wt rows; T symmetric)
      f32x4 acc[4][4] = {};
      gemm128<8>(cWth + mo, cWtl + mo, bi0, cWth + mo, cWtl + mo, bj0, acc, smem, tid);
      #pragma unroll
      for (int fm = 0; fm < 4; ++fm)
        #pragma unroll
        for (int fn = 0; fn < 4; ++fn) {
          int r = bi0 + orow + fm * 16, c = bj0 + ocol + fn * 16;
          #pragma unroll
          for (int v = 0; v < 4; ++v) {
            size_t idx = mo + (size_t)(r + v) * 256 + c;
            split_st(&Th[idx], &Tl[idx], acc[fm][fn][v]);
          }
        }
    }
    grid_bar(cnt, flg, bseq++);
    {  // Wn = 1.5 W - 0.5 W·T  (A = W rows, B = T rows (sym)); also write Wn^T
      f32x4 acc[4][4] = {};
      gemm128<8>(cWh + mo, cWl + mo, bi0, Th + mo, Tl + mo, bj0, acc, smem, tid);
      #pragma unroll
      for (int fm = 0; fm < 4; ++fm)
        #pragma unroll
        for (int fn = 0; fn < 4; ++fn) {
          int r = bi0 + orow + fm * 16, c = bj0 + ocol + fn * 16;
          u16x4 h4, l4;
          #pragma unroll
          for (int v = 0; v < 4; ++v) {
            size_t idx = mo + (size_t)(r + v) * 256 + c;
            float wv = bf2f(cWh[idx]) + bf2f(cWl[idx]);
            float nv = 1.5f * wv - 0.5f * acc[fm][fn][v];
            u16 h = f2bf(nv);
            h4[v] = h; l4[v] = f2bf(nv - bf2f(h));
            nWh[idx] = h; nWl[idx] = l4[v];
          }
          size_t idxT = mo + (size_t)c * 256 + r;   // r % 4 == 0 -> 8B aligned
          *(u16x4*)&nWth[idxT] = h4;
          *(u16x4*)&nWtl[idxT] = l4;
        }
    }
    grid_bar(cnt, flg, bseq++);
    u16* t0;
    t0 = cWh; cWh = nWh; nWh = t0;
    t0 = cWl; cWl = nWl; nWl = t0;
    t0 = cWth; cWth = nWth; nWth = t0;
    t0 = cWtl; cWtl = nWtl; nWtl = t0;
  }
  // after 20 swaps cur == W0

  // ---- stage 4: PQ[t] = masked(O)·masked(O)^T (K=128) ----
  if (bid < 16) {
    int m4 = bid >> 2, til = bid & 3;
    int i0 = (til >> 1) * 128, j0 = (til & 1) * 128;
    const u16* Oh = cWh + (size_t)(1 + m4) * MSZ;
    const u16* Ol = cWl + (size_t)(1 + m4) * MSZ;
    f32x4 acc[4][4] = {};
    gemm128<4>(Oh, Ol, i0, Oh, Ol, j0, acc, smem, tid);
    #pragma unroll
    for (int fm = 0; fm < 4; ++fm)
      #pragma unroll
      for (int fn = 0; fn < 4; ++fn) {
        int r = i0 + orow + fm * 16, c = j0 + ocol + fn * 16;
        #pragma unroll
        for (int v = 0; v < 4; ++v) {
          size_t idx = (size_t)m4 * MSZ + (size_t)(r + v) * 256 + c;
          split_st(&PQh[idx], &PQl[idx], acc[fm][fn][v]);
        }
      }
  }
  grid_bar(cnt, flg, bseq++);

  // ---- stage 5: C1 = PQ0·PQ1, C2 = PQ2·PQ3, C2t = PQ3·PQ2 (PQ symmetric) ----
  if (bid < 12) {
    int z = bid >> 2, til = bid & 3;
    int i0 = (til >> 1) * 128, j0 = (til & 1) * 128;
    int ai = (z == 0) ? 0 : (z == 1) ? 2 : 3;
    int bi = (z == 0) ? 1 : (z == 1) ? 3 : 2;
    u16* oh = (z == 0) ? C1h : (z == 1) ? C2h : C2th;
    u16* ol = (z == 0) ? C1l : (z == 1) ? C2l : C2tl;
    f32x4 acc[4][4] = {};
    gemm128<8>(PQh + (size_t)ai * MSZ, PQl + (size_t)ai * MSZ, i0,
               PQh + (size_t)bi * MSZ, PQl + (size_t)bi * MSZ, j0, acc, smem, tid);
    #pragma unroll
    for (int fm = 0; fm < 4; ++fm)
      #pragma unroll
      for (int fn = 0; fn < 4; ++fn) {
        int r = i0 + orow + fm * 16, c = j0 + ocol + fn * 16;
        #pragma unroll
        for (int v = 0; v < 4; ++v) {
          size_t idx = (size_t)(r + v) * 256 + c;
          split_st(&oh[idx], &ol[idx], acc[fm][fn][v]);
        }
      }
  }
  grid_bar(cnt, flg, bseq++);

  // ---- stage 6: block-orth members: P[0..3] and Q^T[0..3] (elementwise) ----
  {
    for (size_t g = (size_t)bid * 256 + tid; g < 65536; g += NBLK * 256) {
      int row = (int)(g >> 8), col = (int)(g & 255);
      float I = (row == col) ? 1.f : 0.f;
      float p0 = bf2f(PQh[g]) + bf2f(PQl[g]);
      float p1 = bf2f(PQh[MSZ + g]) + bf2f(PQl[MSZ + g]);
      float c1 = bf2f(C1h[g]) + bf2f(C1l[g]);
      split_st(&Ph[g],           &Pl[g],           c1);
      split_st(&Ph[MSZ + g],     &Pl[MSZ + g],     p0 - c1);
      split_st(&Ph[2*MSZ + g],   &Pl[2*MSZ + g],   p1 - c1);
      split_st(&Ph[3*MSZ + g],   &Pl[3*MSZ + g],   I - p0 - p1 + c1);
      float q0 = bf2f(PQh[2*MSZ + g]) + bf2f(PQl[2*MSZ + g]);
      float q1 = bf2f(PQh[3*MSZ + g]) + bf2f(PQl[3*MSZ + g]);
      float c2t = bf2f(C2th[g]) + bf2f(C2tl[g]);
      split_st(&QTh[g],          &QTl[g],          c2t);
      split_st(&QTh[MSZ + g],    &QTl[MSZ + g],    q0 - c2t);
      split_st(&QTh[2*MSZ + g],  &QTl[2*MSZ + g],  q1 - c2t);
      split_st(&QTh[3*MSZ + g],  &QTl[3*MSZ + g],  I - q0 - q1 + c2t);
    }
  }
  grid_bar(cnt, flg, bseq++);

  // ---- stage 7: matrix_conv: R[ij] = sum_t P[tp]·Q[tq]; store R^T ----
  {
    const int toff[10] = {0, 1, 3, 4, 6, 10, 12, 13, 15, 16};
    const int tp[16] = {0, 0, 1, 1, 0, 2, 0, 1, 2, 3, 1, 3, 2, 2, 3, 3};
    const int tq[16] = {0, 1, 0, 1, 2, 0, 3, 2, 1, 0, 3, 1, 2, 3, 2, 3};
    for (int job = bid; job < 36; job += NBLK) {
      int ij = job >> 2, til = job & 3;
      int i0 = (til >> 1) * 128, j0 = (til & 1) * 128;
      f32x4 acc[4][4] = {};
      for (int t = toff[ij]; t < toff[ij + 1]; ++t) {
        gemm128<8>(Ph + (size_t)tp[t] * MSZ, Pl + (size_t)tp[t] * MSZ, i0,
                   QTh + (size_t)tq[t] * MSZ, QTl + (size_t)tq[t] * MSZ, j0, acc, smem, tid);
      }
      #pragma unroll
      for (int fm = 0; fm < 4; ++fm)
        #pragma unroll
        for (int fn = 0; fn < 4; ++fn) {
          int r = i0 + orow + fm * 16, c = j0 + ocol + fn * 16;
          u16x4 h4, l4;
          #pragma unroll
          for (int v = 0; v < 4; ++v) {
            u16 h = f2bf(acc[fm][fn][v]);
            h4[v] = h; l4[v] = f2bf(acc[fm][fn][v] - bf2f(h));
          }
          size_t idxT = (size_t)ij * MSZ + (size_t)c * 256 + r;  // R^T
          *(u16x4*)&RTh[idxT] = h4;
          *(u16x4*)&RTl[idxT] = l4;
        }
    }
  }
  grid_bar(cnt, flg, bseq++);

  // ---- stage 8: Wb[ij][cout][cin] = bf16((H·R[ij])^T) ----
  {
    for (int job = bid; job < 36; job += NBLK) {
      int ij = job >> 2, til = job & 3;
      int i0 = (til >> 1) * 128, j0 = (til & 1) * 128;
      f32x4 acc[4][4] = {};
      gemm128<8>(cWh, cWl, i0, RTh + (size_t)ij * MSZ, RTl + (size_t)ij * MSZ, j0,
                 acc, smem, tid);
      #pragma unroll
      for (int fm = 0; fm < 4; ++fm)
        #pragma unroll
        for (int fn = 0; fn < 4; ++fn) {
          int r = i0 + orow + fm * 16, c = j0 + ocol + fn * 16;
          u16x4 h4;
          #pragma unroll
          for (int v = 0; v < 4; ++v) h4[v] = f2bf(acc[fm][fn][v]);
          *(u16x4*)&WBQ[(size_t)ij * MSZ + (size_t)c * 256 + r] = h4;
        }
    }
  }
}

// ---------------- conv: implicit GEMM, MFMA bf16 (unchanged) ----------------
__global__ __launch_bounds__(512, 2) void conv_k(
    const u16* __restrict__ xb, const u16* __restrict__ Wb,
    const float* __restrict__ bias, float* __restrict__ out) {
  int braw = blockIdx.x;
  int L = (braw & 7) * 128 + (braw >> 3);   // bijective XCD swizzle (1024 % 8 == 0)
  int bn = L & 1, ht = (L >> 1) & 15, n = L >> 5;
  int h0 = ht * 4;
  int tid = threadIdx.x;
  int lane = tid & 63, wave = tid >> 6;
  int wm = wave >> 1, wn = wave & 1;

  __shared__ char smem[65536];
  char* sX = smem;            // 48KB: [r6][w64][128B cin] swizzled
  char* sW = smem + 49152;    // 16KB: [cl128][128B cin] swizzled

  f32x4 acc[4][4] = {};
  uint4 xr[6], wr[2];

  auto loadX = [&](int ct) {
    #pragma unroll
    for (int p = 0; p < 6; ++p) {
      int e = tid + p * 512;
      int cb = (e & 7) * 16;
      int w = (e >> 3) & 63;
      int r = e >> 9;
      int hs = (h0 - 1 + r) & 63;
      xr[p] = *(const uint4*)((const char*)xb + (((size_t)(n * 64 + hs) * 64 + w) << 9) + ct * 128 + cb);
    }
  };
  auto storeX = [&]() {
    #pragma unroll
    for (int p = 0; p < 6; ++p) {
      int e = tid + p * 512;
      int cb = (e & 7) * 16;
      int w = (e >> 3) & 63;
      int r = e >> 9;
      *(uint4*)(sX + (r * 64 + w) * 128 + (cb ^ ((w & 7) << 4))) = xr[p];
    }
  };
  auto loadW = [&](int ct, int tap) {
    #pragma unroll
    for (int p = 0; p < 2; ++p) {
      int e = tid + p * 512;
      int cb = (e & 7) * 16;
      int cl = e >> 3;
      wr[p] = *(const uint4*)((const char*)Wb + ((size_t)(tap * 256 + bn * 128 + cl) << 9) + ct * 128 + cb);
    }
  };
  auto storeW = [&]() {
    #pragma unroll
    for (int p = 0; p < 2; ++p) {
      int e = tid + p * 512;
      int cb = (e & 7) * 16;
      int cl = e >> 3;
      *(uint4*)(sW + cl * 128 + (cb ^ ((cl & 7) << 4))) = wr[p];
    }
  };

  loadX(0); loadW(0, 0);
  storeX(); storeW();
  loadW(0, 1);                 // W prefetch in flight across first barrier
  __syncthreads();

  for (int ct = 0; ct < 4; ++ct) {
    for (int tap = 0; tap < 9; ++tap) {
      int kh = tap % 3, kw = tap / 3;   // tap == ij == kw*3+kh
      #pragma unroll
      for (int ks = 0; ks < 2; ++ks) {
        int kb = ks * 64 + (lane >> 4) * 16;
        bf16x8 af[4], bfr[4];
        #pragma unroll
        for (int fm = 0; fm < 4; ++fm) {
          int wsrc = (fm * 16 + (lane & 15) + kw + 63) & 63;
          af[fm] = *(const bf16x8*)(sX + ((wm + kh) * 64 + wsrc) * 128 + (kb ^ ((wsrc & 7) << 4)));
        }
        #pragma unroll
        for (int fn = 0; fn < 4; ++fn) {
          int cl = wn * 64 + fn * 16 + (lane & 15);
          bfr[fn] = *(const bf16x8*)(sW + cl * 128 + (kb ^ ((cl & 7) << 4)));
        }
        #pragma unroll
        for (int fm = 0; fm < 4; ++fm)
          #pragma unroll
          for (int fn = 0; fn < 4; ++fn)
            acc[fm][fn] = __builtin_amdgcn_mfma_f32_16x16x32_bf16(af[fm], bfr[fn], acc[fm][fn], 0, 0, 0);
      }
      __syncthreads();                  // all waves done reading sW (and sX at tap 8)
      if (tap < 8) {
        storeW();                       // W[tap+1] -> LDS
        if (tap < 7) {
          loadW(ct, tap + 2);
        } else if (ct < 3) {
          loadW(ct + 1, 0);
          loadX(ct + 1);                // X prefetch hides under tap-8 MFMAs
        }
        __syncthreads();
      } else if (ct < 3) {
        storeX();                       // X[ct+1] (regs loaded at tap 7)
        storeW();                       // W[ct+1][0]
        loadW(ct + 1, 1);
        __syncthreads();
      }
    }
  }

  // epilogue through LDS -> full-cacheline f32 stores (no partial-line RMW)
  float* sF = (float*)smem;             // 32KB slice: [c32][h4][w64] f32, swizzled
  __syncthreads();
  #pragma unroll
  for (int fn = 0; fn < 4; ++fn) {
    int cl = wn * 16 + (lane & 15);
    float bv = bias[bn * 128 + wn * 64 + fn * 16 + (lane & 15)];
    #pragma unroll
    for (int fm = 0; fm < 4; ++fm) {
      f32x4 v = acc[fm][fn];
      #pragma unroll
      for (int vv = 0; vv < 4; ++vv) {
        int w = fm * 16 + ((lane >> 4) << 2) + vv;
        *(float*)((char*)sF + (cl * 4 + wm) * 256 + (((unsigned)(w * 4)) ^ ((unsigned)(cl & 15) << 4))) = v[vv] + bv;
      }
    }
    __syncthreads();
    #pragma unroll
    for (int p = 0; p < 4; ++p) {
      int e = tid + p * 512;
      int w4 = e & 15, hh = (e >> 4) & 3, cl2 = e >> 6;
      int wnr = cl2 >> 4, t = cl2 & 15;
      int cg = bn * 128 + wnr * 64 + fn * 16 + t;
      f32x4 val = *(const f32x4*)((const char*)sF + (cl2 * 4 + hh) * 256 + (((unsigned)(w4 * 16)) ^ ((unsigned)(cl2 & 15) << 4)));
      *(f32x4*)(out + (((size_t)n * 256 + cg) * 64 + (h0 + hh)) * 64 + w4 * 4) = val;
    }
    if (fn < 3) __syncthreads();
  }
}

extern "C" void kernel_launch(void* const* d_in, const int* in_sizes, int n_in,
                              void* d_out, int out_size, void* d_ws, size_t ws_size,
                              hipStream_t stream) {
  const float* x = (const float*)d_in[0];
  const float* param = (const float*)d_in[1];
  const float* u0 = (const float*)d_in[2];
  const float* bias = (const float*)d_in[3];
  float* out = (float*)d_out;
  char* ws = (char*)d_ws;
  (void)in_sizes; (void)n_in; (void)out_size; (void)ws_size;

  (void)hipMemsetAsync(ws + O_BAR, 0, 2048, stream);   // zero barrier counters + flags
  convert_k<<<32768, 256, 0, stream>>>(x, (u16*)(ws + O_XB));
  weight_k<<<NBLK, 256, 0, stream>>>(param, u0, ws);
  conv_k<<<1024, 512, 0, stream>>>((const u16*)(ws + O_XB), (const u16*)(ws + O_WBQ), bias, out);
}

// Round 7
// 689.117 us; speedup vs baseline: 3.2768x; 3.2768x over previous
//
#include <hip/hip_runtime.h>
#include <stdint.h>

typedef unsigned short u16;
typedef short bf16x8 __attribute__((ext_vector_type(8)));
typedef float f32x4 __attribute__((ext_vector_type(4)));

#define CDIM 256
#define MSZ 65536

// ---------------- ws layout (bytes) ----------------
constexpr size_t O_XB   = 0;                       // 64MB x bf16 NHWC
constexpr size_t O_AT   = 67108864;                // fp32 A^T (dead after scale)
constexpr size_t O_PQH  = 67108864;                // alias AT
constexpr size_t O_PQL  = O_PQH + 524288;
constexpr size_t O_SVAL = 68419584;
constexpr size_t O_W0   = 68419840;                // h,l,th,tl each 655360 B
constexpr size_t O_W1   = 71041280;
constexpr size_t O_PH   = 71041280;                // alias W1 (dead after bjorck)
constexpr size_t O_PL   = O_PH + 524288;
constexpr size_t O_QTH  = O_PL + 524288;
constexpr size_t O_QTL  = O_QTH + 524288;
constexpr size_t O_TH   = 73662720;
constexpr size_t O_TL   = O_TH + 655360;
constexpr size_t O_C1H  = 73662720;                // alias T (dead after bjorck)
constexpr size_t O_C1L  = O_C1H + 131072;
constexpr size_t O_C2H  = O_C1L + 131072;
constexpr size_t O_C2L  = O_C2H + 131072;
constexpr size_t O_C2TH = O_C2L + 131072;
constexpr size_t O_C2TL = O_C2TH + 131072;
constexpr size_t O_RTH  = 74973440;
constexpr size_t O_RTL  = O_RTH + 1179648;
constexpr size_t O_WBQ  = O_RTL + 1179648;

__device__ __forceinline__ u16 f2bf(float f) {
  union { float f; uint32_t u; } a; a.f = f;
  uint32_t u = a.u;
  uint32_t r = u + 0x7FFFu + ((u >> 16) & 1u);
  return (u16)(r >> 16);
}
__device__ __forceinline__ float bf2f(u16 u) {
  union { uint32_t u; float f; } a; a.u = ((uint32_t)u) << 16; return a.f;
}
__device__ __forceinline__ void split_st(u16* hi, u16* lo, float v) {
  u16 h = f2bf(v);
  *hi = h;
  *lo = f2bf(v - bf2f(h));
}

// ---------------- x: NCHW f32 -> NHWC bf16 ----------------
__global__ void convert_k(const float* __restrict__ x, u16* __restrict__ xb) {
  __shared__ float t[32][33];
  int b = blockIdx.x;
  int ctile = b & 7, wtile = (b >> 3) & 1, h = (b >> 4) & 63, n = b >> 10;
  int c0 = ctile * 32, w0 = wtile * 32;
  int tid = threadIdx.x;
  for (int p = 0; p < 4; p++) {
    int e = tid + p * 256; int cc = e >> 5, ww = e & 31;
    t[cc][ww] = x[(((size_t)n * 256 + c0 + cc) * 64 + h) * 64 + w0 + ww];
  }
  __syncthreads();
  for (int p = 0; p < 4; p++) {
    int e = tid + p * 256; int ww = e >> 5, cc = e & 31;
    xb[(((size_t)n * 64 + h) * 64 + w0 + ww) * 256 + c0 + cc] = f2bf(t[cc][ww]);
  }
}

// ---------------- At = A^T (fp32, for power iteration) ----------------
__global__ void transpose_k(const float* __restrict__ A, float* __restrict__ At) {
  __shared__ float t[32][33];
  int m = blockIdx.y;
  int i0 = (blockIdx.x >> 3) * 32, j0 = (blockIdx.x & 7) * 32;
  int tid = threadIdx.x;
  const float* Am = A + (size_t)m * MSZ;
  float* Atm = At + (size_t)m * MSZ;
  for (int p = 0; p < 4; p++) {
    int e = tid + p * 256; int ii = e >> 5, jj = e & 31;
    t[ii][jj] = Am[(i0 + ii) * CDIM + j0 + jj];
  }
  __syncthreads();
  for (int p = 0; p < 4; p++) {
    int e = tid + p * 256; int jj = e >> 5, ii = e & 31;
    Atm[(j0 + jj) * CDIM + i0 + ii] = t[ii][jj];
  }
}

// ---------------- power iteration: sval[m] = sigma_max ----------------
__global__ void power_k(const float* __restrict__ A, const float* __restrict__ At,
                        const float* __restrict__ u0, float* __restrict__ sval) {
  int m = blockIdx.x; int t = threadIdx.x;
  __shared__ float u[CDIM], v[CDIM], red[4];
  const float* Am = A + (size_t)m * MSZ;
  const float* Atm = At + (size_t)m * MSZ;
  u[t] = u0[m * CDIM + t];
  __syncthreads();
  float nu = 1.0f;
  for (int it = 0; it < 10; ++it) {
    float a1 = 0.f;
    #pragma unroll 4
    for (int i = 0; i < CDIM; i++) a1 += Am[i * CDIM + t] * u[i];
    float ss = a1 * a1;
    for (int off = 32; off; off >>= 1) ss += __shfl_down(ss, off);
    __syncthreads();
    if ((t & 63) == 0) red[t >> 6] = ss;
    __syncthreads();
    float nv = sqrtf(red[0] + red[1] + red[2] + red[3]);
    v[t] = a1 / nv;
    __syncthreads();
    float a2 = 0.f;
    #pragma unroll 4
    for (int j = 0; j < CDIM; j++) a2 += Atm[j * CDIM + t] * v[j];
    float s2 = a2 * a2;
    for (int off = 32; off; off >>= 1) s2 += __shfl_down(s2, off);
    __syncthreads();
    if ((t & 63) == 0) red[t >> 6] = s2;
    __syncthreads();
    nu = sqrtf(red[0] + red[1] + red[2] + red[3]);
    u[t] = a2 / nu;
    __syncthreads();
  }
  if (t == 0) sval[m] = nu;   // sigma = u^T A v = ||Av|| = last norm
}

// ---------------- scale + hi/lo split (W and W^T) ----------------
__global__ void scale_k(const float* __restrict__ param, const float* __restrict__ At,
                        const float* __restrict__ sval,
                        u16* __restrict__ Wh, u16* __restrict__ Wl,
                        u16* __restrict__ Wth, u16* __restrict__ Wtl) {
  size_t idx = (size_t)blockIdx.x * 256 + threadIdx.x;   // 1280 blocks -> 327680
  int m = (int)(idx >> 16);
  float inv = 1.0f / sval[m];
  float v = param[idx] * inv;
  split_st(&Wh[idx], &Wl[idx], v);
  float vt = At[idx] * inv;
  split_st(&Wth[idx], &Wtl[idx], vt);
}

// ---------------- hi/lo-split MFMA 32x32-tile GEMM: C += A·B^T ----------------
// A/B stored [row][k] k-contiguous bf16 (hi+lo). 4 waves, wave (qm,qn) owns one
// 16x16 quadrant. C elem: row=qm*16+(lane>>4)*4+v, col=qn*16+(lane&15).
__device__ __forceinline__ void gemm32_acc(
    const u16* __restrict__ Ah, const u16* __restrict__ Al, int i0,
    const u16* __restrict__ Bh, const u16* __restrict__ Bl, int j0,
    int K, f32x4* acc, char* smem, int tid)
{
  int lane = tid & 63, wave = tid >> 6;
  int qm = wave >> 1, qn = wave & 1;
  int ra = qm * 16 + (lane & 15);
  int rb = qn * 16 + (lane & 15);
  int kb = (lane >> 4) * 16;
  for (int kc = 0; kc < K; kc += 128) {
    __syncthreads();
    #pragma unroll
    for (int p = 0; p < 8; ++p) {
      int e = tid + p * 256;
      int bufi = e >> 9;                 // 0:Ah 1:Al 2:Bh 3:Bl
      int r = (e >> 4) & 31;
      int cb = (e & 15) * 16;
      const u16* srcm = (bufi == 0) ? Ah : (bufi == 1) ? Al : (bufi == 2) ? Bh : Bl;
      int r0 = (bufi < 2) ? i0 : j0;
      const char* src = (const char*)srcm + ((size_t)(r0 + r) * 256 + kc) * 2 + cb;
      *(uint4*)(smem + bufi * 8192 + r * 256 + (cb ^ ((r & 7) << 4))) = *(const uint4*)src;
    }
    __syncthreads();
    #pragma unroll
    for (int ks = 0; ks < 4; ++ks) {
      int kbyte = ks * 64 + kb;
      int oa = ra * 256 + (kbyte ^ ((ra & 7) << 4));
      int ob = rb * 256 + (kbyte ^ ((rb & 7) << 4));
      bf16x8 ah = *(const bf16x8*)(smem + oa);
      bf16x8 al = *(const bf16x8*)(smem + 8192 + oa);
      bf16x8 bh = *(const bf16x8*)(smem + 16384 + ob);
      bf16x8 bl = *(const bf16x8*)(smem + 24576 + ob);
      *acc = __builtin_amdgcn_mfma_f32_16x16x32_bf16(ah, bh, *acc, 0, 0, 0);
      *acc = __builtin_amdgcn_mfma_f32_16x16x32_bf16(ah, bl, *acc, 0, 0, 0);
      *acc = __builtin_amdgcn_mfma_f32_16x16x32_bf16(al, bh, *acc, 0, 0, 0);
    }
  }
}

#define GEMM_IDX \
  int tid = threadIdx.x; \
  int lane = tid & 63, wave = tid >> 6, qm = wave >> 1, qn = wave & 1; \
  int orow = qm * 16 + ((lane >> 4) << 2); \
  int ocol = qn * 16 + (lane & 15); \
  int i0 = (blockIdx.x >> 3) * 32, j0 = (blockIdx.x & 7) * 32; \
  __shared__ char smem[32768];

// ---------------- Bjorck step 1: T = W^T W ----------------
__global__ __launch_bounds__(256) void bjorck_t_k(
    const u16* __restrict__ Wth, const u16* __restrict__ Wtl,
    u16* __restrict__ Th, u16* __restrict__ Tl) {
  GEMM_IDX
  size_t mo = (size_t)blockIdx.y * MSZ;
  f32x4 acc = {};
  gemm32_acc(Wth + mo, Wtl + mo, i0, Wth + mo, Wtl + mo, j0, 256, &acc, smem, tid);
  #pragma unroll
  for (int v = 0; v < 4; ++v) {
    size_t idx = mo + (size_t)(i0 + orow + v) * 256 + (j0 + ocol);
    split_st(&Th[idx], &Tl[idx], acc[v]);
  }
}

// ---------------- Bjorck step 2: Wn = 1.5W - 0.5 W·T (+ Wn^T) ----------------
__global__ __launch_bounds__(256) void bjorck_u_k(
    const u16* __restrict__ Wh, const u16* __restrict__ Wl,
    const u16* __restrict__ Th, const u16* __restrict__ Tl,
    u16* __restrict__ nWh, u16* __restrict__ nWl,
    u16* __restrict__ nWth, u16* __restrict__ nWtl) {
  GEMM_IDX
  size_t mo = (size_t)blockIdx.y * MSZ;
  f32x4 acc = {};
  gemm32_acc(Wh + mo, Wl + mo, i0, Th + mo, Tl + mo, j0, 256, &acc, smem, tid);
  #pragma unroll
  for (int v = 0; v < 4; ++v) {
    int r = i0 + orow + v, c = j0 + ocol;
    size_t idx = mo + (size_t)r * 256 + c;
    float wv = bf2f(Wh[idx]) + bf2f(Wl[idx]);
    float nv = 1.5f * wv - 0.5f * acc[v];
    split_st(&nWh[idx], &nWl[idx], nv);
    size_t idxT = mo + (size_t)c * 256 + r;
    split_st(&nWth[idxT], &nWtl[idxT], nv);
  }
}

// ---------------- PQ[t] = masked(O)·masked(O)^T (K=128) ----------------
__global__ __launch_bounds__(256) void pq_k(
    const u16* __restrict__ Wh, const u16* __restrict__ Wl,
    u16* __restrict__ PQh, u16* __restrict__ PQl) {
  GEMM_IDX
  int m4 = blockIdx.y;
  const u16* Oh = Wh + (size_t)(1 + m4) * MSZ;
  const u16* Ol = Wl + (size_t)(1 + m4) * MSZ;
  f32x4 acc = {};
  gemm32_acc(Oh, Ol, i0, Oh, Ol, j0, 128, &acc, smem, tid);
  #pragma unroll
  for (int v = 0; v < 4; ++v) {
    size_t idx = (size_t)m4 * MSZ + (size_t)(i0 + orow + v) * 256 + (j0 + ocol);
    split_st(&PQh[idx], &PQl[idx], acc[v]);
  }
}

// ---------------- C1 = PQ0·PQ1, C2 = PQ2·PQ3, C2t = PQ3·PQ2 ----------------
__global__ __launch_bounds__(256) void c12_k(
    const u16* __restrict__ PQh, const u16* __restrict__ PQl,
    u16* __restrict__ C1h, u16* __restrict__ C1l,
    u16* __restrict__ C2h, u16* __restrict__ C2l,
    u16* __restrict__ C2th, u16* __restrict__ C2tl) {
  GEMM_IDX
  int z = blockIdx.y;
  int ai = (z == 0) ? 0 : (z == 1) ? 2 : 3;
  int bi = (z == 0) ? 1 : (z == 1) ? 3 : 2;
  u16* oh = (z == 0) ? C1h : (z == 1) ? C2h : C2th;
  u16* ol = (z == 0) ? C1l : (z == 1) ? C2l : C2tl;
  f32x4 acc = {};
  gemm32_acc(PQh + (size_t)ai * MSZ, PQl + (size_t)ai * MSZ, i0,
             PQh + (size_t)bi * MSZ, PQl + (size_t)bi * MSZ, j0, 256, &acc, smem, tid);
  #pragma unroll
  for (int v = 0; v < 4; ++v) {
    size_t idx = (size_t)(i0 + orow + v) * 256 + (j0 + ocol);
    split_st(&oh[idx], &ol[idx], acc[v]);
  }
}

// ---------------- block-orth members: P[0..3], Q^T[0..3] (elementwise) ----------------
__global__ void blocks_k(const u16* __restrict__ PQh, const u16* __restrict__ PQl,
                         const u16* __restrict__ C1h, const u16* __restrict__ C1l,
                         const u16* __restrict__ C2th, const u16* __restrict__ C2tl,
                         u16* __restrict__ Ph, u16* __restrict__ Pl,
                         u16* __restrict__ QTh, u16* __restrict__ QTl) {
  size_t g = (size_t)blockIdx.x * 256 + threadIdx.x;   // 256 blocks -> 65536
  int row = (int)(g >> 8), col = (int)(g & 255);
  float I = (row == col) ? 1.f : 0.f;
  float p0 = bf2f(PQh[g]) + bf2f(PQl[g]);
  float p1 = bf2f(PQh[MSZ + g]) + bf2f(PQl[MSZ + g]);
  float c1 = bf2f(C1h[g]) + bf2f(C1l[g]);
  split_st(&Ph[g],           &Pl[g],           c1);
  split_st(&Ph[MSZ + g],     &Pl[MSZ + g],     p0 - c1);
  split_st(&Ph[2*MSZ + g],   &Pl[2*MSZ + g],   p1 - c1);
  split_st(&Ph[3*MSZ + g],   &Pl[3*MSZ + g],   I - p0 - p1 + c1);
  float q0 = bf2f(PQh[2*MSZ + g]) + bf2f(PQl[2*MSZ + g]);
  float q1 = bf2f(PQh[3*MSZ + g]) + bf2f(PQl[3*MSZ + g]);
  float c2t = bf2f(C2th[g]) + bf2f(C2tl[g]);
  split_st(&QTh[g],          &QTl[g],          c2t);
  split_st(&QTh[MSZ + g],    &QTl[MSZ + g],    q0 - c2t);
  split_st(&QTh[2*MSZ + g],  &QTl[2*MSZ + g],  q1 - c2t);
  split_st(&QTh[3*MSZ + g],  &QTl[3*MSZ + g],  I - q0 - q1 + c2t);
}

// ---------------- matrix_conv: R[ij] = sum_t P[tp]·Q[tq]; store R^T ----------------
__global__ __launch_bounds__(256) void mconv_k(
    const u16* __restrict__ Ph, const u16* __restrict__ Pl,
    const u16* __restrict__ QTh, const u16* __restrict__ QTl,
    u16* __restrict__ RTh, u16* __restrict__ RTl) {
  GEMM_IDX
  int ij = blockIdx.y;
  const int toff[10] = {0, 1, 3, 4, 6, 10, 12, 13, 15, 16};
  const int tp[16] = {0, 0, 1, 1, 0, 2, 0, 1, 2, 3, 1, 3, 2, 2, 3, 3};
  const int tq[16] = {0, 1, 0, 1, 2, 0, 3, 2, 1, 0, 3, 1, 2, 3, 2, 3};
  f32x4 acc = {};
  for (int t = toff[ij]; t < toff[ij + 1]; ++t) {
    gemm32_acc(Ph + (size_t)tp[t] * MSZ, Pl + (size_t)tp[t] * MSZ, i0,
               QTh + (size_t)tq[t] * MSZ, QTl + (size_t)tq[t] * MSZ, j0, 256, &acc, smem, tid);
  }
  #pragma unroll
  for (int v = 0; v < 4; ++v) {
    int r = i0 + orow + v, c = j0 + ocol;
    size_t idxT = (size_t)ij * MSZ + (size_t)c * 256 + r;  // R^T
    split_st(&RTh[idxT], &RTl[idxT], acc[v]);
  }
}

// ---------------- Wb[ij][cout][cin] = bf16((H·R[ij])^T) ----------------
__global__ __launch_bounds__(256) void final_k(
    const u16* __restrict__ Hh, const u16* __restrict__ Hl,
    const u16* __restrict__ RTh, const u16* __restrict__ RTl,
    u16* __restrict__ WBQ) {
  GEMM_IDX
  int ij = blockIdx.y;
  f32x4 acc = {};
  gemm32_acc(Hh, Hl, i0, RTh + (size_t)ij * MSZ, RTl + (size_t)ij * MSZ, j0,
             256, &acc, smem, tid);
  #pragma unroll
  for (int v = 0; v < 4; ++v) {
    int r = i0 + orow + v, c = j0 + ocol;
    WBQ[(size_t)ij * MSZ + (size_t)c * 256 + r] = f2bf(acc[v]);
  }
}

// ---------------- conv: implicit GEMM, MFMA bf16 (unchanged) ----------------
__global__ __launch_bounds__(512, 2) void conv_k(
    const u16* __restrict__ xb, const u16* __restrict__ Wb,
    const float* __restrict__ bias, float* __restrict__ out) {
  int braw = blockIdx.x;
  int L = (braw & 7) * 128 + (braw >> 3);   // bijective XCD swizzle (1024 % 8 == 0)
  int bn = L & 1, ht = (L >> 1) & 15, n = L >> 5;
  int h0 = ht * 4;
  int tid = threadIdx.x;
  int lane = tid & 63, wave = tid >> 6;
  int wm = wave >> 1, wn = wave & 1;

  __shared__ char smem[65536];
  char* sX = smem;            // 48KB: [r6][w64][128B cin] swizzled
  char* sW = smem + 49152;    // 16KB: [cl128][128B cin] swizzled

  f32x4 acc[4][4] = {};
  uint4 xr[6], wr[2];

  auto loadX = [&](int ct) {
    #pragma unroll
    for (int p = 0; p < 6; ++p) {
      int e = tid + p * 512;
      int cb = (e & 7) * 16;
      int w = (e >> 3) & 63;
      int r = e >> 9;
      int hs = (h0 - 1 + r) & 63;
      xr[p] = *(const uint4*)((const char*)xb + (((size_t)(n * 64 + hs) * 64 + w) << 9) + ct * 128 + cb);
    }
  };
  auto storeX = [&]() {
    #pragma unroll
    for (int p = 0; p < 6; ++p) {
      int e = tid + p * 512;
      int cb = (e & 7) * 16;
      int w = (e >> 3) & 63;
      int r = e >> 9;
      *(uint4*)(sX + (r * 64 + w) * 128 + (cb ^ ((w & 7) << 4))) = xr[p];
    }
  };
  auto loadW = [&](int ct, int tap) {
    #pragma unroll
    for (int p = 0; p < 2; ++p) {
      int e = tid + p * 512;
      int cb = (e & 7) * 16;
      int cl = e >> 3;
      wr[p] = *(const uint4*)((const char*)Wb + ((size_t)(tap * 256 + bn * 128 + cl) << 9) + ct * 128 + cb);
    }
  };
  auto storeW = [&]() {
    #pragma unroll
    for (int p = 0; p < 2; ++p) {
      int e = tid + p * 512;
      int cb = (e & 7) * 16;
      int cl = e >> 3;
      *(uint4*)(sW + cl * 128 + (cb ^ ((cl & 7) << 4))) = wr[p];
    }
  };

  loadX(0); loadW(0, 0);
  storeX(); storeW();
  loadW(0, 1);                 // W prefetch in flight across first barrier
  __syncthreads();

  for (int ct = 0; ct < 4; ++ct) {
    for (int tap = 0; tap < 9; ++tap) {
      int kh = tap % 3, kw = tap / 3;   // tap == ij == kw*3+kh
      #pragma unroll
      for (int ks = 0; ks < 2; ++ks) {
        int kb = ks * 64 + (lane >> 4) * 16;
        bf16x8 af[4], bfr[4];
        #pragma unroll
        for (int fm = 0; fm < 4; ++fm) {
          int wsrc = (fm * 16 + (lane & 15) + kw + 63) & 63;
          af[fm] = *(const bf16x8*)(sX + ((wm + kh) * 64 + wsrc) * 128 + (kb ^ ((wsrc & 7) << 4)));
        }
        #pragma unroll
        for (int fn = 0; fn < 4; ++fn) {
          int cl = wn * 64 + fn * 16 + (lane & 15);
          bfr[fn] = *(const bf16x8*)(sW + cl * 128 + (kb ^ ((cl & 7) << 4)));
        }
        #pragma unroll
        for (int fm = 0; fm < 4; ++fm)
          #pragma unroll
          for (int fn = 0; fn < 4; ++fn)
            acc[fm][fn] = __builtin_amdgcn_mfma_f32_16x16x32_bf16(af[fm], bfr[fn], acc[fm][fn], 0, 0, 0);
      }
      __syncthreads();                  // all waves done reading sW (and sX at tap 8)
      if (tap < 8) {
        storeW();                       // W[tap+1] -> LDS
        if (tap < 7) {
          loadW(ct, tap + 2);
        } else if (ct < 3) {
          loadW(ct + 1, 0);
          loadX(ct + 1);                // X prefetch hides under tap-8 MFMAs
        }
        __syncthreads();
      } else if (ct < 3) {
        storeX();                       // X[ct+1] (regs loaded at tap 7)
        storeW();                       // W[ct+1][0]
        loadW(ct + 1, 1);
        __syncthreads();
      }
    }
  }

  // epilogue through LDS -> full-cacheline f32 stores (no partial-line RMW)
  float* sF = (float*)smem;             // 32KB slice: [c32][h4][w64] f32, swizzled
  __syncthreads();
  #pragma unroll
  for (int fn = 0; fn < 4; ++fn) {
    int cl = wn * 16 + (lane & 15);
    float bv = bias[bn * 128 + wn * 64 + fn * 16 + (lane & 15)];
    #pragma unroll
    for (int fm = 0; fm < 4; ++fm) {
      f32x4 v = acc[fm][fn];
      #pragma unroll
      for (int vv = 0; vv < 4; ++vv) {
        int w = fm * 16 + ((lane >> 4) << 2) + vv;
        *(float*)((char*)sF + (cl * 4 + wm) * 256 + (((unsigned)(w * 4)) ^ ((unsigned)(cl & 15) << 4))) = v[vv] + bv;
      }
    }
    __syncthreads();
    #pragma unroll
    for (int p = 0; p < 4; ++p) {
      int e = tid + p * 512;
      int w4 = e & 15, hh = (e >> 4) & 3, cl2 = e >> 6;
      int wnr = cl2 >> 4, t = cl2 & 15;
      int cg = bn * 128 + wnr * 64 + fn * 16 + t;
      f32x4 val = *(const f32x4*)((const char*)sF + (cl2 * 4 + hh) * 256 + (((unsigned)(w4 * 16)) ^ ((unsigned)(cl2 & 15) << 4)));
      *(f32x4*)(out + (((size_t)n * 256 + cg) * 64 + (h0 + hh)) * 64 + w4 * 4) = val;
    }
    if (fn < 3) __syncthreads();
  }
}

extern "C" void kernel_launch(void* const* d_in, const int* in_sizes, int n_in,
                              void* d_out, int out_size, void* d_ws, size_t ws_size,
                              hipStream_t stream) {
  const float* x = (const float*)d_in[0];
  const float* param = (const float*)d_in[1];
  const float* u0 = (const float*)d_in[2];
  const float* bias = (const float*)d_in[3];
  float* out = (float*)d_out;
  char* ws = (char*)d_ws;
  (void)in_sizes; (void)n_in; (void)out_size; (void)ws_size;

  float* At = (float*)(ws + O_AT);
  float* sval = (float*)(ws + O_SVAL);
  u16* W0h  = (u16*)(ws + O_W0);   u16* W0l  = W0h + 327680;
  u16* W0th = W0l + 327680;        u16* W0tl = W0th + 327680;
  u16* W1h  = (u16*)(ws + O_W1);   u16* W1l  = W1h + 327680;
  u16* W1th = W1l + 327680;        u16* W1tl = W1th + 327680;
  u16* Th = (u16*)(ws + O_TH);     u16* Tl = (u16*)(ws + O_TL);
  u16* PQh = (u16*)(ws + O_PQH);   u16* PQl = (u16*)(ws + O_PQL);
  u16* C1h = (u16*)(ws + O_C1H);   u16* C1l = (u16*)(ws + O_C1L);
  u16* C2h = (u16*)(ws + O_C2H);   u16* C2l = (u16*)(ws + O_C2L);
  u16* C2th = (u16*)(ws + O_C2TH); u16* C2tl = (u16*)(ws + O_C2TL);
  u16* Ph = (u16*)(ws + O_PH);     u16* Pl = (u16*)(ws + O_PL);
  u16* QTh = (u16*)(ws + O_QTH);   u16* QTl = (u16*)(ws + O_QTL);
  u16* RTh = (u16*)(ws + O_RTH);   u16* RTl = (u16*)(ws + O_RTL);
  u16* WBQ = (u16*)(ws + O_WBQ);

  convert_k<<<32768, 256, 0, stream>>>(x, (u16*)(ws + O_XB));
  transpose_k<<<dim3(64, 5), 256, 0, stream>>>(param, At);
  power_k<<<5, 256, 0, stream>>>(param, At, u0, sval);
  scale_k<<<1280, 256, 0, stream>>>(param, At, sval, W0h, W0l, W0th, W0tl);

  u16 *cWh = W0h, *cWl = W0l, *cWth = W0th, *cWtl = W0tl;
  u16 *nWh = W1h, *nWl = W1l, *nWth = W1th, *nWtl = W1tl;
  for (int it = 0; it < 20; ++it) {
    bjorck_t_k<<<dim3(64, 5), 256, 0, stream>>>(cWth, cWtl, Th, Tl);
    bjorck_u_k<<<dim3(64, 5), 256, 0, stream>>>(cWh, cWl, Th, Tl, nWh, nWl, nWth, nWtl);
    u16* t0;
    t0 = cWh; cWh = nWh; nWh = t0;
    t0 = cWl; cWl = nWl; nWl = t0;
    t0 = cWth; cWth = nWth; nWth = t0;
    t0 = cWtl; cWtl = nWtl; nWtl = t0;
  }
  // after 20 swaps cur == W0; W1 region is dead -> P/QT alias is safe

  pq_k<<<dim3(64, 4), 256, 0, stream>>>(cWh, cWl, PQh, PQl);
  c12_k<<<dim3(64, 3), 256, 0, stream>>>(PQh, PQl, C1h, C1l, C2h, C2l, C2th, C2tl);
  blocks_k<<<256, 256, 0, stream>>>(PQh, PQl, C1h, C1l, C2th, C2tl, Ph, Pl, QTh, QTl);
  mconv_k<<<dim3(64, 9), 256, 0, stream>>>(Ph, Pl, QTh, QTl, RTh, RTl);
  final_k<<<dim3(64, 9), 256, 0, stream>>>(cWh, cWl, RTh, RTl, WBQ);

  conv_k<<<1024, 512, 0, stream>>>((const u16*)(ws + O_XB), WBQ, bias, out);
}